// Round 5
// baseline (293.902 us; speedup 1.0000x reference)
//
#include <hip/hip_runtime.h>
#include <math.h>

typedef float v2f __attribute__((ext_vector_type(2)));

namespace {
constexpr int   M1 = 12;     // basis per dim
constexpr float LB = 4.5f;   // HSGP half-domain L = c * S = 1.5 * 3.0
}

// ---------------------------------------------------------------------------
// Setup: fold spectral-density sqrt weights + norm into beta, laid out per
// lane-class q = (a_half*2 + j_half), padded to 20 floats per a-row:
//   ws[q*120 + r*20 + (d*3 + jp)*2 + p] = B(a = 6*(q>>1)+r, d, j = 6*(q&1)+2*jp+p)
// (indices 18,19 of each row are zero padding so rows are float4-aligned)
// ---------------------------------------------------------------------------
__global__ void setup_B_kernel(const float* __restrict__ beta,
                               const float* __restrict__ ls,
                               const float* __restrict__ alpha,
                               float* __restrict__ Bs) {
    int idx = blockIdx.x * blockDim.x + threadIdx.x;
    if (idx >= 480) return;
    int q   = idx / 120;
    int rem = idx - q * 120;
    int r   = rem / 20;
    int rr  = rem - r * 20;
    if (rr >= 18) { Bs[idx] = 0.0f; return; }
    int pi = rr >> 1;
    int p  = rr & 1;
    int d  = pi / 3;
    int jp = pi % 3;
    int a = (q >> 1) * 6 + r;
    int j = (q & 1) * 6 + jp * 2 + p;
    float w0 = (float)M_PI * (float)(a + 1) / (2.0f * LB);
    float w1 = (float)M_PI * (float)(j + 1) / (2.0f * LB);
    float l0 = ls[0], l1 = ls[1], al = alpha[0];
    float S = al * al * (2.0f * (float)M_PI) * l0 * l1 *
              expf(-0.5f * (l0 * l0 * w0 * w0 + l1 * l1 * w1 * w1));
    Bs[idx] = beta[d * (M1 * M1) + a * M1 + j] * sqrtf(S) * (1.0f / LB);
}

// ---------------------------------------------------------------------------
// quad (4-lane) butterfly sum via DPP quad_perm — pure VALU, no LDS
// ---------------------------------------------------------------------------
__device__ __forceinline__ float quad_sum(float v) {
    int t = __builtin_amdgcn_mov_dpp(__float_as_int(v), 0xB1, 0xF, 0xF, true); // [1,0,3,2]
    v += __int_as_float(t);
    t = __builtin_amdgcn_mov_dpp(__float_as_int(v), 0x4E, 0xF, 0xF, true);     // [2,3,0,1]
    v += __int_as_float(t);
    return v;
}

// ---------------------------------------------------------------------------
// 3 packed (sin, W*m*cos) pairs for multiples m = bm+1 .. bm+6 of angle th.
// ---------------------------------------------------------------------------
__device__ __forceinline__ void trig3(float th, float bm, const v2f* pkW,
                                      v2f* ps, v2f* pwc) {
    float s1 = __sinf(th), c1 = __cosf(th);
    float sb = __sinf(bm * th), cb = __cosf(bm * th);
    float sA = fmaf(sb, c1,  cb * s1);           // bm+1
    float cA = fmaf(cb, c1, -(sb * s1));
    float sB = fmaf(sA, c1,  cA * s1);           // bm+2
    float cB = fmaf(cA, c1, -(sA * s1));
    float s2 = 2.0f * s1 * c1;                   // double angle for packed step
    float c2 = fmaf(-2.0f * s1, s1, 1.0f);
    v2f P = (v2f){sA, sB}, C = (v2f){cA, cB};
    v2f c2p = (v2f){c2, c2}, s2p = (v2f){s2, s2};
    ps[0] = P; pwc[0] = pkW[0] * C;
    v2f P1 = __builtin_elementwise_fma(P, c2p, C * s2p);
    v2f C1 = __builtin_elementwise_fma(C, c2p, -(P * s2p));
    ps[1] = P1; pwc[1] = pkW[1] * C1;
    v2f P2 = __builtin_elementwise_fma(P1, c2p, C1 * s2p);
    v2f C2 = __builtin_elementwise_fma(C1, c2p, -(P1 * s2p));
    ps[2] = P2; pwc[2] = pkW[2] * C2;
}

// ---------------------------------------------------------------------------
// Main: 4 lanes per element; lane q = (a_half<<1)|j_half owns a 6x6 block of
// the 12x12 basis grid. B-block lives in LDS (1920 B/block) and is re-read
// per step: 4 distinct addresses per wave read (q-strided 480 B -> disjoint
// bank quads + broadcast) = conflict-free, ~64-cyc pipelined — vs rounds
// 2-4 where the register allocator (capped at 124-128 VGPRs) spilled the
// 108-float table to scratch and re-read it through L2 every step.
// ---------------------------------------------------------------------------
__global__ __launch_bounds__(64)
void geo_kernel(const float* __restrict__ xg, const float* __restrict__ vg,
                const float* __restrict__ Bs, float* __restrict__ out, int B)
{
    __shared__ float4 lB4[120];
    float* lB = reinterpret_cast<float*>(lB4);

    // ---- stage B-table into LDS (single-wave block) ----
    {
        const float4* src = reinterpret_cast<const float4*>(Bs);
        int l = threadIdx.x;
        lB4[l] = src[l];
        if (l < 56) lB4[l + 64] = src[l + 64];
    }
    __syncthreads();

    int tid = blockIdx.x * 64 + threadIdx.x;
    int e = tid >> 2;
    if (e >= B) return;
    int q  = tid & 3;
    int qa = q >> 1, qj = q & 1;
    const int qbase = q * 120;

    const float W = (float)M_PI / (2.0f * LB);
    float bm0 = (float)(6 * qa);
    float bm1 = (float)(6 * qj);
    v2f pkW0[3], pkW1[3];
    #pragma unroll
    for (int k = 0; k < 3; ++k) {
        pkW0[k] = (v2f){W * (bm0 + (float)(2 * k + 1)), W * (bm0 + (float)(2 * k + 2))};
        pkW1[k] = (v2f){W * (bm1 + (float)(2 * k + 1)), W * (bm1 + (float)(2 * k + 2))};
    }

    float2 xv = reinterpret_cast<const float2*>(xg)[e];
    float2 vv2 = reinterpret_cast<const float2*>(vg)[e];
    float x0 = xv.x, x1 = xv.y, v0 = vv2.x, v1 = vv2.y;

    // per-lane scalar output slot: out[t][q>>1][e][q&1]
    unsigned off = 4u * ((((unsigned)qa * (unsigned)B) + (unsigned)e) * 2u + (unsigned)qj);
    const unsigned stride = 16u * (unsigned)B;      // bytes per time slot
    char* outc = reinterpret_cast<char*>(out);
    {
        float sval = (q & 2) ? ((q & 1) ? v1 : v0) : ((q & 1) ? x1 : x0);
        *reinterpret_cast<float*>(outc + off) = sval;
    }

    // Adams histories (older entries), named regs
    float h1x = 0.f, h2x = 0.f, h3x = 0.f, h1y = 0.f, h2y = 0.f, h3y = 0.f;
    float g1x = 0.f, g2x = 0.f, g3x = 0.f, g1y = 0.f, g2y = 0.f, g3y = 0.f;
    const float h = 1.0f / 99.0f;

    auto STEP = [&](float c0, float c1c, float c2c, float c3c) {
        v2f ps0[3], pwc0[3], ps1[3], pwc1[3];
        trig3(W * (x0 + LB), bm0, pkW0, ps0, pwc0);
        trig3(W * (x1 + LB), bm1, pkW1, ps1, pwc1);

        v2f pf0{0,0}, pf1{0,0}, pf2{0,0};
        v2f pdA0{0,0}, pdA1{0,0}, pdA2{0,0};
        v2f pdB0{0,0}, pdB1{0,0}, pdB2{0,0};
        #pragma unroll
        for (int r = 0; r < 6; ++r) {
            const float* Lp = lB + qbase + r * 20;
            float4 L0 = *reinterpret_cast<const float4*>(Lp);
            float4 L1 = *reinterpret_cast<const float4*>(Lp + 4);
            float4 L2 = *reinterpret_cast<const float4*>(Lp + 8);
            float4 L3 = *reinterpret_cast<const float4*>(Lp + 12);
            float2 L4 = *reinterpret_cast<const float2*>(Lp + 16);
            v2f B00 = (v2f){L0.x, L0.y}, B01 = (v2f){L0.z, L0.w}, B02 = (v2f){L1.x, L1.y};
            v2f B10 = (v2f){L1.z, L1.w}, B11 = (v2f){L2.x, L2.y}, B12 = (v2f){L2.z, L2.w};
            v2f B20 = (v2f){L3.x, L3.y}, B21 = (v2f){L3.z, L3.w}, B22 = (v2f){L4.x, L4.y};

            float sA = (r & 1) ? ps0[r >> 1].y : ps0[r >> 1].x;
            float cA = (r & 1) ? pwc0[r >> 1].y : pwc0[r >> 1].x;
            v2f aS0{0,0}, aS1{0,0}, aS2{0,0}, aC0{0,0}, aC1{0,0}, aC2{0,0};
            aS0 = __builtin_elementwise_fma(B00, ps1[0], aS0);
            aC0 = __builtin_elementwise_fma(B00, pwc1[0], aC0);
            aS0 = __builtin_elementwise_fma(B01, ps1[1], aS0);
            aC0 = __builtin_elementwise_fma(B01, pwc1[1], aC0);
            aS0 = __builtin_elementwise_fma(B02, ps1[2], aS0);
            aC0 = __builtin_elementwise_fma(B02, pwc1[2], aC0);
            aS1 = __builtin_elementwise_fma(B10, ps1[0], aS1);
            aC1 = __builtin_elementwise_fma(B10, pwc1[0], aC1);
            aS1 = __builtin_elementwise_fma(B11, ps1[1], aS1);
            aC1 = __builtin_elementwise_fma(B11, pwc1[1], aC1);
            aS1 = __builtin_elementwise_fma(B12, ps1[2], aS1);
            aC1 = __builtin_elementwise_fma(B12, pwc1[2], aC1);
            aS2 = __builtin_elementwise_fma(B20, ps1[0], aS2);
            aC2 = __builtin_elementwise_fma(B20, pwc1[0], aC2);
            aS2 = __builtin_elementwise_fma(B21, ps1[1], aS2);
            aC2 = __builtin_elementwise_fma(B21, pwc1[1], aC2);
            aS2 = __builtin_elementwise_fma(B22, ps1[2], aS2);
            aC2 = __builtin_elementwise_fma(B22, pwc1[2], aC2);

            v2f sAp = (v2f){sA, sA}, cAp = (v2f){cA, cA};
            pf0  = __builtin_elementwise_fma(sAp, aS0, pf0);
            pf1  = __builtin_elementwise_fma(sAp, aS1, pf1);
            pf2  = __builtin_elementwise_fma(sAp, aS2, pf2);
            pdA0 = __builtin_elementwise_fma(cAp, aS0, pdA0);
            pdA1 = __builtin_elementwise_fma(cAp, aS1, pdA1);
            pdA2 = __builtin_elementwise_fma(cAp, aS2, pdA2);
            pdB0 = __builtin_elementwise_fma(sAp, aC0, pdB0);
            pdB1 = __builtin_elementwise_fma(sAp, aC1, pdB1);
            pdB2 = __builtin_elementwise_fma(sAp, aC2, pdB2);
        }

        // packed vv fold (quad-uniform) before the horizontal adds
        float vv00 = v0 * v0, vv01 = v0 * v1, vv11 = v1 * v1;
        float vv00x2 = vv00 + vv00, vv01x2 = vv01 + vv01, vv11x2 = vv11 + vv11;
        v2f Q0 = __builtin_elementwise_fma(pdB1, (v2f){vv11x2, vv11x2},
                                           -(pdA2 * (v2f){vv11, vv11}));
        Q0 = __builtin_elementwise_fma(pdB0, (v2f){vv01x2, vv01x2}, Q0);
        Q0 = __builtin_elementwise_fma(pdA0, (v2f){vv00, vv00}, Q0);
        v2f Q1 = __builtin_elementwise_fma(pdA2, (v2f){vv01x2, vv01x2},
                                           pdB2 * (v2f){vv11, vv11});
        Q1 = __builtin_elementwise_fma(pdA1, (v2f){vv00x2, vv00x2}, Q1);
        Q1 = __builtin_elementwise_fma(pdB0, (v2f){-vv00, -vv00}, Q1);

        float f0 = pf0.x + pf0.y, f1 = pf1.x + pf1.y, f2 = pf2.x + pf2.y;
        float q0s = Q0.x + Q0.y, q1s = Q1.x + Q1.y;

        f0 = quad_sum(f0); f1 = quad_sum(f1); f2 = quad_sum(f2);
        q0s = quad_sum(q0s); q1s = quad_sum(q1s);

        float G00 = f0 + 1.0f, G01 = f1, G11 = f2 + 1.0f;
        float det = fmaf(G00, G11, -(G01 * G01));
        float rdet = __builtin_amdgcn_rcpf(det);
        float a0 = -0.5f * rdet * fmaf(G11, q0s, -(G01 * q1s));
        float a1 = -0.5f * rdet * fmaf(G00, q1s, -(G01 * q0s));

        // AB combine: newest derivative is (v, a); histories are older
        float dx0 = fmaf(c0, v0, fmaf(c1c, h1x, fmaf(c2c, h2x, c3c * h3x)));
        float dx1 = fmaf(c0, v1, fmaf(c1c, h1y, fmaf(c2c, h2y, c3c * h3y)));
        float dv0 = fmaf(c0, a0, fmaf(c1c, g1x, fmaf(c2c, g2x, c3c * g3x)));
        float dv1 = fmaf(c0, a1, fmaf(c1c, g1y, fmaf(c2c, g2y, c3c * g3y)));
        h3x = h2x; h2x = h1x; h1x = v0;  h3y = h2y; h2y = h1y; h1y = v1;
        g3x = g2x; g2x = g1x; g1x = a0;  g3y = g2y; g2y = g1y; g1y = a1;
        x0 = fmaf(h, dx0, x0); x1 = fmaf(h, dx1, x1);
        v0 = fmaf(h, dv0, v0); v1 = fmaf(h, dv1, v1);

        off += stride;
        float sval = (q & 2) ? ((q & 1) ? v1 : v0) : ((q & 1) ? x1 : x0);
        *reinterpret_cast<float*>(outc + off) = sval;
    };

    // startup (orders 1..3), then steady AB4
    STEP(1.0f, 0.0f, 0.0f, 0.0f);
    STEP(1.5f, -0.5f, 0.0f, 0.0f);
    STEP(23.0f / 12.0f, -16.0f / 12.0f, 5.0f / 12.0f, 0.0f);
    #pragma unroll 2
    for (int t = 3; t < 99; ++t)
        STEP(55.0f / 24.0f, -59.0f / 24.0f, 37.0f / 24.0f, -9.0f / 24.0f);
}

// ---------------------------------------------------------------------------
extern "C" void kernel_launch(void* const* d_in, const int* in_sizes, int n_in,
                              void* d_out, int out_size, void* d_ws, size_t ws_size,
                              hipStream_t stream) {
    const float* x0    = (const float*)d_in[0];
    const float* v0    = (const float*)d_in[1];
    const float* beta  = (const float*)d_in[2];
    const float* ls    = (const float*)d_in[3];
    const float* alpha = (const float*)d_in[4];
    float* out = (float*)d_out;
    float* Bs  = (float*)d_ws;   // 480 floats, padded per-lane-class layout

    int B = in_sizes[0] / 2;     // 50000

    hipLaunchKernelGGL(setup_B_kernel, dim3(8), dim3(64), 0, stream,
                       beta, ls, alpha, Bs);

    long threads = 4L * B;
    int grid = (int)((threads + 63) / 64);
    hipLaunchKernelGGL(geo_kernel, dim3(grid), dim3(64), 0, stream,
                       x0, v0, Bs, out, B);
}

// Round 6
// 139.247 us; speedup vs baseline: 2.1107x; 2.1107x over previous
//
#include <hip/hip_runtime.h>
#include <math.h>

typedef _Float16 h4 __attribute__((ext_vector_type(4)));
typedef float    f4 __attribute__((ext_vector_type(4)));

namespace {
constexpr float LB = 4.5f;                       // HSGP half-domain
constexpr float WF = (float)M_PI / (2.0f * LB);  // base frequency
}

// ---------------------------------------------------------------------------
// Setup: build the 3 shared A-fragments for v_mfma_f32_16x16x16_f16.
// A_d[row=a][k=j] = beta[d, a*12+j] * sqrt(S(a,j)) / LB, padded to 16x16.
// Fragment layout: lane l holds A[l&15][4*(l>>4)+t], t=0..3.
// ws layout: A[d*256 + l*4 + t] as _Float16 (768 halfs).
// ---------------------------------------------------------------------------
__global__ void setup_A_kernel(const float* __restrict__ beta,
                               const float* __restrict__ ls,
                               const float* __restrict__ alpha,
                               _Float16* __restrict__ A) {
    int idx = blockIdx.x * blockDim.x + threadIdx.x;
    if (idx >= 768) return;
    int d = idx >> 8;
    int l = (idx >> 2) & 63;
    int t = idx & 3;
    int r = l & 15;                 // output row = a index
    int k = ((l >> 4) << 2) + t;    // K index   = j index
    float val = 0.0f;
    if (r < 12 && k < 12) {
        float w0 = WF * (float)(r + 1);
        float w1 = WF * (float)(k + 1);
        float l0 = ls[0], l1 = ls[1], al = alpha[0];
        float S = al * al * (2.0f * (float)M_PI) * l0 * l1 *
                  expf(-0.5f * (l0 * l0 * w0 * w0 + l1 * l1 * w1 * w1));
        val = beta[d * 144 + r * 12 + k] * sqrtf(S) * (1.0f / LB);
    }
    A[idx] = (_Float16)val;
}

// ---------------------------------------------------------------------------
// 4 consecutive multiples mb..mb+3 of angle th: s[t]=sin((mb+t)th),
// c[t]=cos((mb+t)th), via HW sincos at the base + angle-addition.
// ---------------------------------------------------------------------------
__device__ __forceinline__ void trig4(float th, float mb, float* s, float* c) {
    float s1 = __sinf(th), c1 = __cosf(th);
    float sb = __sinf(mb * th), cb = __cosf(mb * th);
    s[0] = sb; c[0] = cb;
    #pragma unroll
    for (int t = 1; t < 4; ++t) {
        s[t] = fmaf(s[t - 1], c1,  c[t - 1] * s1);
        c[t] = fmaf(c[t - 1], c1, -(s[t - 1] * s1));
    }
}

// ---------------------------------------------------------------------------
// Main: one wave integrates 16 elements. Element = lane&15 (replicated over
// the 4 lane-groups g=lane>>4). Per step: per-lane trig for multiples
// 4g+1..4g+4 of both dims; 6 MFMAs compute u_d = M_d*s1, w_d = M_d*wc1 for
// all 16 elements; each lane folds its 4 a-rows (C/D row = 4g+reg) with
// s0/wc0 weights; __shfl_xor(16/32) completes the a-sum; Christoffel + AB
// epilogue replicated on all 4 copies.
// ---------------------------------------------------------------------------
__global__ __launch_bounds__(256)
void geo_kernel(const float* __restrict__ xg, const float* __restrict__ vg,
                const _Float16* Ag /* non-restrict: pins afrag in regs */,
                float* __restrict__ out, int B)
{
    int lane = threadIdx.x & 63;
    int wave = (blockIdx.x * 256 + threadIdx.x) >> 6;
    int ebase = wave << 4;
    if (ebase >= B) return;
    int g = lane >> 4;
    int e = ebase + (lane & 15);
    if (e >= B) e = B - 1;          // safe clamp (B%16==0 in practice)

    // ---- shared A fragments (6 VGPRs) ----
    union U8 { uint2 u; h4 h; };
    const uint2* Au = reinterpret_cast<const uint2*>(Ag);
    U8 a0, a1, a2;
    a0.u = Au[0 * 64 + lane];
    a1.u = Au[1 * 64 + lane];
    a2.u = Au[2 * 64 + lane];
    asm volatile("" ::: "memory");  // forbid reload of Ag inside the loop
    h4 A0 = a0.h, A1 = a1.h, A2 = a2.h;

    // per-lane multiple base and W*(mb+t) constants
    float mb = (float)(4 * g + 1);
    float Wm[4];
    #pragma unroll
    for (int t = 0; t < 4; ++t) Wm[t] = WF * (mb + (float)t);

    float2 xv = reinterpret_cast<const float2*>(xg)[e];
    float2 vv2 = reinterpret_cast<const float2*>(vg)[e];
    float x0 = xv.x, x1 = xv.y, v0 = vv2.x, v1 = vv2.y;

    // per-lane output slot: out[t][g>>1][e][g&1]
    unsigned off = 4u * ((((unsigned)(g >> 1) * (unsigned)B) + (unsigned)e) * 2u
                         + (unsigned)(g & 1));
    const unsigned stride = 16u * (unsigned)B;   // bytes per time slot
    char* outc = reinterpret_cast<char*>(out);
    {
        float sval = (g & 2) ? ((g & 1) ? v1 : v0) : ((g & 1) ? x1 : x0);
        *reinterpret_cast<float*>(outc + off) = sval;
    }

    // Adams histories (older entries)
    float h1x = 0.f, h2x = 0.f, h3x = 0.f, h1y = 0.f, h2y = 0.f, h3y = 0.f;
    float g1x = 0.f, g2x = 0.f, g3x = 0.f, g1y = 0.f, g2y = 0.f, g3y = 0.f;
    const float h = 1.0f / 99.0f;

    auto STEP = [&](float c0, float c1c, float c2c, float c3c) {
        // ---- per-lane trig: multiples 4g+1..4g+4 of th0 (fold side, f32)
        //      and of th1 (MFMA B side, packed to f16) ----
        float s0v[4], c0v[4], s1v[4], c1v[4], wc0[4];
        trig4(WF * (x0 + LB), mb, s0v, c0v);
        trig4(WF * (x1 + LB), mb, s1v, c1v);
        #pragma unroll
        for (int t = 0; t < 4; ++t) wc0[t] = Wm[t] * c0v[t];

        h4 bs, bc;
        #pragma unroll
        for (int t = 0; t < 4; ++t) {
            bs[t] = (_Float16)s1v[t];
            bc[t] = (_Float16)(Wm[t] * c1v[t]);
        }

        // ---- matrix pipe: u_d = M_d * s1, w_d = M_d * wc1 (16 elems/wave) --
        f4 z = {0.f, 0.f, 0.f, 0.f};
        f4 u0 = __builtin_amdgcn_mfma_f32_16x16x16f16(A0, bs, z, 0, 0, 0);
        f4 u1 = __builtin_amdgcn_mfma_f32_16x16x16f16(A1, bs, z, 0, 0, 0);
        f4 u2 = __builtin_amdgcn_mfma_f32_16x16x16f16(A2, bs, z, 0, 0, 0);
        f4 w0 = __builtin_amdgcn_mfma_f32_16x16x16f16(A0, bc, z, 0, 0, 0);
        f4 w1 = __builtin_amdgcn_mfma_f32_16x16x16f16(A1, bc, z, 0, 0, 0);
        f4 w2 = __builtin_amdgcn_mfma_f32_16x16x16f16(A2, bc, z, 0, 0, 0);

        // ---- fold this lane's 4 a-rows (rows 4g..4g+3) ----
        float f0 = 0.f, f1 = 0.f, f2 = 0.f;
        float dA0 = 0.f, dA1 = 0.f, dA2 = 0.f;
        float dB0 = 0.f, dB1 = 0.f, dB2 = 0.f;
        #pragma unroll
        for (int t = 0; t < 4; ++t) {
            float sA = s0v[t], cA = wc0[t];
            f0  = fmaf(sA, u0[t], f0);   dA0 = fmaf(cA, u0[t], dA0);
            f1  = fmaf(sA, u1[t], f1);   dA1 = fmaf(cA, u1[t], dA1);
            f2  = fmaf(sA, u2[t], f2);   dA2 = fmaf(cA, u2[t], dA2);
            dB0 = fmaf(sA, w0[t], dB0);
            dB1 = fmaf(sA, w1[t], dB1);
            dB2 = fmaf(sA, w2[t], dB2);
        }

        // ---- fold vv (element-uniform) before the cross-lane reduce ----
        float vv00 = v0 * v0, vv01 = v0 * v1, vv11 = v1 * v1;
        float q0p = dA0 * vv00 + 2.0f * dB0 * vv01 + fmaf(2.0f, dB1, -dA2) * vv11;
        float q1p = fmaf(2.0f, dA1, -dB0) * vv00 + 2.0f * dA2 * vv01 + dB2 * vv11;

        // ---- reduce over the 4 lane-groups (same element) ----
        f0  += __shfl_xor(f0, 16);  f0  += __shfl_xor(f0, 32);
        f1  += __shfl_xor(f1, 16);  f1  += __shfl_xor(f1, 32);
        f2  += __shfl_xor(f2, 16);  f2  += __shfl_xor(f2, 32);
        q0p += __shfl_xor(q0p, 16); q0p += __shfl_xor(q0p, 32);
        q1p += __shfl_xor(q1p, 16); q1p += __shfl_xor(q1p, 32);

        // ---- 2x2 Christoffel acceleration ----
        float G00 = f0 + 1.0f, G01 = f1, G11 = f2 + 1.0f;
        float det = fmaf(G00, G11, -(G01 * G01));
        float rdet = __builtin_amdgcn_rcpf(det);
        float a0v = -0.5f * rdet * fmaf(G11, q0p, -(G01 * q1p));
        float a1v = -0.5f * rdet * fmaf(G00, q1p, -(G01 * q0p));

        // ---- Adams-Bashforth update ----
        float dx0 = fmaf(c0, v0, fmaf(c1c, h1x, fmaf(c2c, h2x, c3c * h3x)));
        float dx1 = fmaf(c0, v1, fmaf(c1c, h1y, fmaf(c2c, h2y, c3c * h3y)));
        float dv0 = fmaf(c0, a0v, fmaf(c1c, g1x, fmaf(c2c, g2x, c3c * g3x)));
        float dv1 = fmaf(c0, a1v, fmaf(c1c, g1y, fmaf(c2c, g2y, c3c * g3y)));
        h3x = h2x; h2x = h1x; h1x = v0;  h3y = h2y; h2y = h1y; h1y = v1;
        g3x = g2x; g2x = g1x; g1x = a0v; g3y = g2y; g2y = g1y; g1y = a1v;
        x0 = fmaf(h, dx0, x0); x1 = fmaf(h, dx1, x1);
        v0 = fmaf(h, dv0, v0); v1 = fmaf(h, dv1, v1);

        off += stride;
        float sval = (g & 2) ? ((g & 1) ? v1 : v0) : ((g & 1) ? x1 : x0);
        *reinterpret_cast<float*>(outc + off) = sval;
    };

    // startup (orders 1..3), then steady AB4
    STEP(1.0f, 0.0f, 0.0f, 0.0f);
    STEP(1.5f, -0.5f, 0.0f, 0.0f);
    STEP(23.0f / 12.0f, -16.0f / 12.0f, 5.0f / 12.0f, 0.0f);
    #pragma unroll 2
    for (int t = 3; t < 99; ++t)
        STEP(55.0f / 24.0f, -59.0f / 24.0f, 37.0f / 24.0f, -9.0f / 24.0f);
}

// ---------------------------------------------------------------------------
extern "C" void kernel_launch(void* const* d_in, const int* in_sizes, int n_in,
                              void* d_out, int out_size, void* d_ws, size_t ws_size,
                              hipStream_t stream) {
    const float* x0    = (const float*)d_in[0];
    const float* v0    = (const float*)d_in[1];
    const float* beta  = (const float*)d_in[2];
    const float* ls    = (const float*)d_in[3];
    const float* alpha = (const float*)d_in[4];
    float* out = (float*)d_out;
    _Float16* A = (_Float16*)d_ws;   // 768 halfs: 3 MFMA A-fragments

    int B = in_sizes[0] / 2;         // 50000

    hipLaunchKernelGGL(setup_A_kernel, dim3(12), dim3(64), 0, stream,
                       beta, ls, alpha, A);

    int waves = (B + 15) / 16;                   // 3125
    int grid  = (waves + 3) / 4;                 // 4 waves (256 thr) per block
    hipLaunchKernelGGL(geo_kernel, dim3(grid), dim3(256), 0, stream,
                       x0, v0, A, out, B);
}